// Round 1
// baseline (831.202 us; speedup 1.0000x reference)
//
#include <hip/hip_runtime.h>

#define T_SEQ 4096
#define D_EMB 768
#define N_HEAD 12
#define D_HEAD 64
#define D_MLP 3072
#define NTOK 8192   // B*T

typedef __bf16 v8bf __attribute__((ext_vector_type(8)));
typedef float v4f __attribute__((ext_vector_type(4)));

__device__ __forceinline__ unsigned short f2bf(float f) {
    unsigned int u = __float_as_uint(f);
    unsigned int r = (u + 0x7fffu + ((u >> 16) & 1u)) >> 16;
    return (unsigned short)r;
}

// ---------------- weight cast + transpose: fp32 [K][N] -> bf16 [N][K] --------
__global__ void tcast_kernel(const float* __restrict__ in, unsigned short* __restrict__ out,
                             int K, int N) {
    __shared__ float tile[32][33];
    int k0 = blockIdx.y * 32, n0 = blockIdx.x * 32;
    int tx = threadIdx.x, ty = threadIdx.y;
    for (int i = ty; i < 32; i += 8)
        tile[i][tx] = in[(size_t)(k0 + i) * N + n0 + tx];
    __syncthreads();
    for (int i = ty; i < 32; i += 8)
        out[(size_t)(n0 + i) * K + k0 + tx] = f2bf(tile[tx][i]);
}

// ---------------- LayerNorm (768 wide), fp32 in -> bf16 out ------------------
__global__ __launch_bounds__(256) void ln_kernel(const float* __restrict__ x,
                                                 const float* __restrict__ g,
                                                 const float* __restrict__ bta,
                                                 unsigned short* __restrict__ out) {
    int row = blockIdx.x;
    const float* xr = x + (size_t)row * D_EMB;
    int tid = threadIdx.x;
    float v[3];
    float s = 0.f, s2 = 0.f;
#pragma unroll
    for (int i = 0; i < 3; i++) {
        v[i] = xr[tid + i * 256];
        s += v[i];
        s2 += v[i] * v[i];
    }
#pragma unroll
    for (int o = 1; o < 64; o <<= 1) {
        s += __shfl_xor(s, o);
        s2 += __shfl_xor(s2, o);
    }
    __shared__ float red[8];
    int wave = tid >> 6, lane = tid & 63;
    if (lane == 0) { red[wave] = s; red[wave + 4] = s2; }
    __syncthreads();
    s = red[0] + red[1] + red[2] + red[3];
    s2 = red[4] + red[5] + red[6] + red[7];
    float mu = s * (1.f / 768.f);
    float var = s2 * (1.f / 768.f) - mu * mu;
    float rstd = rsqrtf(var + 1e-5f);
#pragma unroll
    for (int i = 0; i < 3; i++) {
        int c = tid + i * 256;
        out[(size_t)row * D_EMB + c] = f2bf((v[i] - mu) * rstd * g[c] + bta[c]);
    }
}

// ---------------- GEMM: C[M,N] = A[M,K] * Bt[N,K]^T, bf16 in, fp32 acc -------
// 128x128 tile, BK=32, 256 threads = 4 waves in 2x2, each wave 64x64 (4x4 mfma)
// EPI 0: qkv scatter -> Q/K/V [B][H][T][64] bf16
// EPI 1: outF = acc + bias[col] + resid[row*768+col]   (N=768, fp32 out)
// EPI 2: outB = gelu(acc + bias[col])                  (N=3072, bf16 out)
template <int EPI>
__global__ __launch_bounds__(256) void gemm_kernel(
    const unsigned short* __restrict__ A, const unsigned short* __restrict__ Bt, int K,
    const float* __restrict__ bias, const float* __restrict__ resid,
    float* __restrict__ outF, unsigned short* __restrict__ outB,
    unsigned short* __restrict__ Qb, unsigned short* __restrict__ Kb,
    unsigned short* __restrict__ Vb) {
    __shared__ unsigned short As[128 * 40];
    __shared__ unsigned short Bs[128 * 40];
    const int tid = threadIdx.x;
    const int wave = tid >> 6, lane = tid & 63;
    const int wm = wave >> 1, wn = wave & 1;
    const int n16 = lane & 15, kq = lane >> 4;
    const long m0 = (long)blockIdx.y * 128, nb0 = (long)blockIdx.x * 128;

    const v4f vzero = {0.f, 0.f, 0.f, 0.f};
    v4f acc[4][4];
#pragma unroll
    for (int mi = 0; mi < 4; mi++)
#pragma unroll
        for (int ni = 0; ni < 4; ni++) acc[mi][ni] = vzero;

    for (int k0 = 0; k0 < K; k0 += 32) {
#pragma unroll
        for (int i = 0; i < 2; i++) {
            int c = tid + i * 256;
            int row = c >> 2, cc = (c & 3) << 3;
            *(uint4*)(&As[row * 40 + cc]) = *(const uint4*)(&A[(m0 + row) * K + k0 + cc]);
            *(uint4*)(&Bs[row * 40 + cc]) = *(const uint4*)(&Bt[(nb0 + row) * K + k0 + cc]);
        }
        __syncthreads();
        v8bf af[4], bfr[4];
#pragma unroll
        for (int i = 0; i < 4; i++) {
            af[i] = *(const v8bf*)(&As[(wm * 64 + i * 16 + n16) * 40 + kq * 8]);
            bfr[i] = *(const v8bf*)(&Bs[(wn * 64 + i * 16 + n16) * 40 + kq * 8]);
        }
#pragma unroll
        for (int mi = 0; mi < 4; mi++)
#pragma unroll
            for (int ni = 0; ni < 4; ni++)
                acc[mi][ni] = __builtin_amdgcn_mfma_f32_16x16x32_bf16(af[mi], bfr[ni],
                                                                     acc[mi][ni], 0, 0, 0);
        __syncthreads();
    }

    // epilogue: C/D layout col=lane&15, row=(lane>>4)*4+reg  [m89 verified]
#pragma unroll
    for (int mi = 0; mi < 4; mi++) {
#pragma unroll
        for (int ni = 0; ni < 4; ni++) {
#pragma unroll
            for (int r = 0; r < 4; r++) {
                long row = m0 + wm * 64 + mi * 16 + kq * 4 + r;
                long col = nb0 + wn * 64 + ni * 16 + n16;
                float v = acc[mi][ni][r];
                if (EPI == 0) {
                    int which = (int)(col / 768);
                    int c = (int)(col % 768);
                    int hh = c >> 6, ii = c & 63;
                    int bb = (int)(row >> 12), t = (int)(row & 4095);
                    size_t dst = (((size_t)bb * N_HEAD + hh) * T_SEQ + t) * D_HEAD + ii;
                    unsigned short bv = f2bf(v);
                    if (which == 0) Qb[dst] = bv;
                    else if (which == 1) Kb[dst] = bv;
                    else Vb[dst] = bv;
                } else if (EPI == 1) {
                    outF[row * 768 + col] = v + bias[col] + resid[row * 768 + col];
                } else {
                    float t = v + bias[col];
                    outB[row * 3072 + col] = f2bf(0.5f * t * (1.f + erff(t * 0.70710678118f)));
                }
            }
        }
    }
}

// ---------------- Flash attention (causal), bf16 QKV -> bf16 y ---------------
// block = (b,h,qt): 64 queries; 4 waves x 16 q-rows; k-tiles of 64 keys, kt<=qt
__global__ __launch_bounds__(256) void attn_kernel(const unsigned short* __restrict__ Q,
                                                   const unsigned short* __restrict__ Kg,
                                                   const unsigned short* __restrict__ Vg,
                                                   unsigned short* __restrict__ y) {
    __shared__ unsigned short Vs[64 * 68];       // V tile, padded stride 68
    __shared__ unsigned short Ps[4 * 16 * 64];   // per-wave P bands
    const int tid = threadIdx.x;
    const int wave = tid >> 6, lane = tid & 63;
    const int n16 = lane & 15, kq = lane >> 4;
    const int qt = blockIdx.x, h = blockIdx.y, b = blockIdx.z;
    const size_t hoff = (((size_t)b * N_HEAD + h) * T_SEQ) * D_HEAD;
    const unsigned short* Qh = Q + hoff;
    const unsigned short* Kh = Kg + hoff;
    const unsigned short* Vh = Vg + hoff;

    // Q fragments for this wave's 16 rows (A-operand: A[m=lane&15][k=quad*8+j])
    v8bf qf[2];
    const int qrow = qt * 64 + wave * 16 + n16;
#pragma unroll
    for (int ks = 0; ks < 2; ks++)
        qf[ks] = *(const v8bf*)(&Qh[(size_t)qrow * D_HEAD + ks * 32 + kq * 8]);

    const v4f vzero = {0.f, 0.f, 0.f, 0.f};
    v4f o[4];
    float m_i[4], l_i[4];
#pragma unroll
    for (int r = 0; r < 4; r++) { m_i[r] = -__builtin_inff(); l_i[r] = 0.f; }
#pragma unroll
    for (int nt = 0; nt < 4; nt++) o[nt] = vzero;

    unsigned short* Pw = &Ps[wave * 16 * 64];

    for (int kt = 0; kt <= qt; ++kt) {
        __syncthreads();  // protect Vs/Ps reads of previous iteration
        // stage V tile (64x64) -> Vs (stride 68), 8B chunks, coalesced
#pragma unroll
        for (int i = 0; i < 4; i++) {
            int c = tid + i * 256;
            int vr = c >> 4, vc = (c & 15) * 4;
            *(uint2*)(&Vs[vr * 68 + vc]) =
                *(const uint2*)(&Vh[((size_t)kt * 64 + vr) * D_HEAD + vc]);
        }
        // S = Q * K^T (K fragments direct from global: contiguous in dh)
        v4f s[4];
#pragma unroll
        for (int nt = 0; nt < 4; nt++) s[nt] = vzero;
#pragma unroll
        for (int nt = 0; nt < 4; nt++)
#pragma unroll
            for (int ks = 0; ks < 2; ks++) {
                v8bf kf = *(const v8bf*)(
                    &Kh[((size_t)kt * 64 + nt * 16 + n16) * D_HEAD + ks * 32 + kq * 8]);
                s[nt] = __builtin_amdgcn_mfma_f32_16x16x32_bf16(qf[ks], kf, s[nt], 0, 0, 0);
            }
        // scale + causal mask (only diagonal tile needs masking)
        const int qbase = qt * 64 + wave * 16 + kq * 4;
#pragma unroll
        for (int nt = 0; nt < 4; nt++)
#pragma unroll
            for (int r = 0; r < 4; r++) {
                float v = s[nt][r] * 0.125f;
                if (kt == qt) {
                    int key = kt * 64 + nt * 16 + n16;
                    if (key > qbase + r) v = -__builtin_inff();
                }
                s[nt][r] = v;
            }
        // online softmax (row reductions across the 16 lanes of each quad)
#pragma unroll
        for (int r = 0; r < 4; r++) {
            float mx = fmaxf(fmaxf(s[0][r], s[1][r]), fmaxf(s[2][r], s[3][r]));
            mx = fmaxf(mx, __shfl_xor(mx, 1));
            mx = fmaxf(mx, __shfl_xor(mx, 2));
            mx = fmaxf(mx, __shfl_xor(mx, 4));
            mx = fmaxf(mx, __shfl_xor(mx, 8));
            float mnew = fmaxf(m_i[r], mx);
            float alpha = __expf(m_i[r] - mnew);
            m_i[r] = mnew;
            float ps = 0.f;
#pragma unroll
            for (int nt = 0; nt < 4; nt++) {
                float p = __expf(s[nt][r] - mnew);
                s[nt][r] = p;
                ps += p;
            }
            ps += __shfl_xor(ps, 1);
            ps += __shfl_xor(ps, 2);
            ps += __shfl_xor(ps, 4);
            ps += __shfl_xor(ps, 8);
            l_i[r] = l_i[r] * alpha + ps;
#pragma unroll
            for (int nt = 0; nt < 4; nt++) o[nt][r] *= alpha;
        }
        // P (C-layout) -> LDS -> reload as A-operand  [m120 pattern]
#pragma unroll
        for (int nt = 0; nt < 4; nt++)
#pragma unroll
            for (int r = 0; r < 4; r++)
                Pw[(kq * 4 + r) * 64 + nt * 16 + n16] = f2bf(s[nt][r]);
        __syncthreads();  // Vs staged + Ps visible
        // O += P * V
#pragma unroll
        for (int ks = 0; ks < 2; ks++) {
            v8bf pa = *(const v8bf*)(&Pw[n16 * 64 + ks * 32 + kq * 8]);
#pragma unroll
            for (int nt = 0; nt < 4; nt++) {
                v8bf vb;
#pragma unroll
                for (int j = 0; j < 8; j++)
                    ((unsigned short*)&vb)[j] = Vs[(ks * 32 + kq * 8 + j) * 68 + nt * 16 + n16];
                o[nt] = __builtin_amdgcn_mfma_f32_16x16x32_bf16(pa, vb, o[nt], 0, 0, 0);
            }
        }
    }
    // epilogue: y[b][t][h*64+i] bf16
#pragma unroll
    for (int nt = 0; nt < 4; nt++)
#pragma unroll
        for (int r = 0; r < 4; r++) {
            int q = qt * 64 + wave * 16 + kq * 4 + r;
            float val = o[nt][r] / l_i[r];
            y[((size_t)b * T_SEQ + q) * D_EMB + h * 64 + nt * 16 + n16] = f2bf(val);
        }
}

// ---------------- launch -----------------------------------------------------
extern "C" void kernel_launch(void* const* d_in, const int* in_sizes, int n_in,
                              void* d_out, int out_size, void* d_ws, size_t ws_size,
                              hipStream_t stream) {
    const float* x = (const float*)d_in[0];
    const float* ln1_g = (const float*)d_in[1];
    const float* ln1_b = (const float*)d_in[2];
    const float* wqkv_w = (const float*)d_in[3];
    const float* wo_w = (const float*)d_in[4];
    const float* wo_b = (const float*)d_in[5];
    const float* ln2_g = (const float*)d_in[6];
    const float* ln2_b = (const float*)d_in[7];
    const float* w1_w = (const float*)d_in[8];
    const float* w1_b = (const float*)d_in[9];
    const float* w2_w = (const float*)d_in[10];
    const float* w2_b = (const float*)d_in[11];
    float* out = (float*)d_out;

    char* ws = (char*)d_ws;
    size_t off = 0;
    auto alloc = [&](size_t bytes) -> void* {
        void* p = ws + off;
        off += (bytes + 255) & ~(size_t)255;
        return p;
    };
    unsigned short* xn = (unsigned short*)alloc((size_t)NTOK * D_EMB * 2);        // ln out (reused)
    unsigned short* wqkvT = (unsigned short*)alloc((size_t)2304 * 768 * 2);
    unsigned short* woT = (unsigned short*)alloc((size_t)768 * 768 * 2);
    unsigned short* w1T = (unsigned short*)alloc((size_t)3072 * 768 * 2);
    unsigned short* w2T = (unsigned short*)alloc((size_t)768 * 3072 * 2);
    unsigned short* Qb = (unsigned short*)alloc((size_t)NTOK * D_EMB * 2);
    unsigned short* Kb = (unsigned short*)alloc((size_t)NTOK * D_EMB * 2);
    unsigned short* Vb = (unsigned short*)alloc((size_t)NTOK * D_EMB * 2);
    unsigned short* yb = (unsigned short*)alloc((size_t)NTOK * D_EMB * 2);
    float* res1 = (float*)alloc((size_t)NTOK * D_EMB * 4);
    unsigned short* hbuf = Qb;  // overlay: Q/K/V/y dead before w1 GEMM writes h (50.3 MB)

    dim3 tb(32, 8);
    tcast_kernel<<<dim3(2304 / 32, 768 / 32), tb, 0, stream>>>(wqkv_w, wqkvT, 768, 2304);
    tcast_kernel<<<dim3(768 / 32, 768 / 32), tb, 0, stream>>>(wo_w, woT, 768, 768);
    tcast_kernel<<<dim3(3072 / 32, 768 / 32), tb, 0, stream>>>(w1_w, w1T, 768, 3072);
    tcast_kernel<<<dim3(768 / 32, 3072 / 32), tb, 0, stream>>>(w2_w, w2T, 3072, 768);

    ln_kernel<<<NTOK, 256, 0, stream>>>(x, ln1_g, ln1_b, xn);

    gemm_kernel<0><<<dim3(2304 / 128, NTOK / 128), 256, 0, stream>>>(
        xn, wqkvT, 768, nullptr, nullptr, nullptr, nullptr, Qb, Kb, Vb);

    attn_kernel<<<dim3(T_SEQ / 64, N_HEAD, 2), 256, 0, stream>>>(Qb, Kb, Vb, yb);

    gemm_kernel<1><<<dim3(768 / 128, NTOK / 128), 256, 0, stream>>>(
        yb, woT, 768, wo_b, x, res1, nullptr, nullptr, nullptr, nullptr);

    ln_kernel<<<NTOK, 256, 0, stream>>>(res1, ln2_g, ln2_b, xn);

    gemm_kernel<2><<<dim3(3072 / 128, NTOK / 128), 256, 0, stream>>>(
        xn, w1T, 768, w1_b, nullptr, nullptr, hbuf, nullptr, nullptr, nullptr);

    gemm_kernel<1><<<dim3(768 / 128, NTOK / 128), 256, 0, stream>>>(
        hbuf, w2T, 3072, w2_b, res1, out, nullptr, nullptr, nullptr, nullptr);
}

// Round 2
// 719.722 us; speedup vs baseline: 1.1549x; 1.1549x over previous
//
#include <hip/hip_runtime.h>

#define T_SEQ 4096
#define D_EMB 768
#define N_HEAD 12
#define D_HEAD 64
#define D_MLP 3072
#define NTOK 8192   // B*T

typedef __bf16 v8bf __attribute__((ext_vector_type(8)));
typedef float v4f __attribute__((ext_vector_type(4)));

__device__ __forceinline__ unsigned short f2bf(float f) {
    unsigned int u = __float_as_uint(f);
    unsigned int r = (u + 0x7fffu + ((u >> 16) & 1u)) >> 16;
    return (unsigned short)r;
}

__device__ __forceinline__ void g2lds16(const void* g, void* l) {
    __builtin_amdgcn_global_load_lds(
        (const __attribute__((address_space(1))) void*)g,
        (__attribute__((address_space(3))) void*)l, 16, 0, 0);
}

// ---------------- weight cast + transpose: fp32 [K][N] -> bf16 [N][K] --------
__global__ void tcast_kernel(const float* __restrict__ in, unsigned short* __restrict__ out,
                             int K, int N) {
    __shared__ float tile[32][33];
    int k0 = blockIdx.y * 32, n0 = blockIdx.x * 32;
    int tx = threadIdx.x, ty = threadIdx.y;
    for (int i = ty; i < 32; i += 8)
        tile[i][tx] = in[(size_t)(k0 + i) * N + n0 + tx];
    __syncthreads();
    for (int i = ty; i < 32; i += 8)
        out[(size_t)(n0 + i) * K + k0 + tx] = f2bf(tile[tx][i]);
}

// ---------------- V transpose: [bh][t][64] -> [bh][64][t] bf16 ---------------
__global__ void vtrans_kernel(const unsigned short* __restrict__ in,
                              unsigned short* __restrict__ out) {
    __shared__ unsigned short tile[32][33];
    size_t base = (size_t)blockIdx.z * T_SEQ * D_HEAD;
    int t0 = blockIdx.x * 32, d0 = blockIdx.y * 32;
    int tx = threadIdx.x, ty = threadIdx.y;
    for (int i = ty; i < 32; i += 8)
        tile[i][tx] = in[base + (size_t)(t0 + i) * D_HEAD + d0 + tx];
    __syncthreads();
    for (int i = ty; i < 32; i += 8)
        out[base + (size_t)(d0 + i) * T_SEQ + t0 + tx] = tile[tx][i];
}

// ---------------- LayerNorm (768 wide), fp32 in -> bf16 out ------------------
__global__ __launch_bounds__(256) void ln_kernel(const float* __restrict__ x,
                                                 const float* __restrict__ g,
                                                 const float* __restrict__ bta,
                                                 unsigned short* __restrict__ out) {
    int row = blockIdx.x;
    const float* xr = x + (size_t)row * D_EMB;
    int tid = threadIdx.x;
    float v[3];
    float s = 0.f, s2 = 0.f;
#pragma unroll
    for (int i = 0; i < 3; i++) {
        v[i] = xr[tid + i * 256];
        s += v[i];
        s2 += v[i] * v[i];
    }
#pragma unroll
    for (int o = 1; o < 64; o <<= 1) {
        s += __shfl_xor(s, o);
        s2 += __shfl_xor(s2, o);
    }
    __shared__ float red[8];
    int wave = tid >> 6, lane = tid & 63;
    if (lane == 0) { red[wave] = s; red[wave + 4] = s2; }
    __syncthreads();
    s = red[0] + red[1] + red[2] + red[3];
    s2 = red[4] + red[5] + red[6] + red[7];
    float mu = s * (1.f / 768.f);
    float var = s2 * (1.f / 768.f) - mu * mu;
    float rstd = rsqrtf(var + 1e-5f);
#pragma unroll
    for (int i = 0; i < 3; i++) {
        int c = tid + i * 256;
        out[(size_t)row * D_EMB + c] = f2bf((v[i] - mu) * rstd * g[c] + bta[c]);
    }
}

// ---------------- GEMM: C[M,N] = A[M,K] * Bt[N,K]^T, bf16 in, fp32 acc -------
// m97 structure: 128x128 tile, BK=32, global_load_lds width=16, unpadded LDS.
// EPI 0: qkv scatter -> Q/K/V [B][H][T][64] bf16
// EPI 1: outF = acc + bias[col] + resid[row*768+col]   (N=768, fp32 out)
// EPI 2: outB = gelu(acc + bias[col])                  (N=3072, bf16 out)
template <int EPI>
__global__ __launch_bounds__(256) void gemm_kernel(
    const unsigned short* __restrict__ A, const unsigned short* __restrict__ Bt, int K,
    const float* __restrict__ bias, const float* __restrict__ resid,
    float* __restrict__ outF, unsigned short* __restrict__ outB,
    unsigned short* __restrict__ Qb, unsigned short* __restrict__ Kb,
    unsigned short* __restrict__ Vb) {
    __shared__ unsigned short As[128 * 32];
    __shared__ unsigned short Bs[128 * 32];
    const int tid = threadIdx.x;
    const int wave = tid >> 6, lane = tid & 63;
    const int wm = wave >> 1, wn = wave & 1;
    const int n16 = lane & 15, kq = lane >> 4;
    const long m0 = (long)blockIdx.y * 128, nb0 = (long)blockIdx.x * 128;

    const v4f vzero = {0.f, 0.f, 0.f, 0.f};
    v4f acc[4][4];
#pragma unroll
    for (int mi = 0; mi < 4; mi++)
#pragma unroll
        for (int ni = 0; ni < 4; ni++) acc[mi][ni] = vzero;

    for (int k0 = 0; k0 < K; k0 += 32) {
        // stage 8KB A-tile + 8KB B-tile via global_load_lds (16B/lane)
        // chunk c = (wave*2+i)*64 + lane covers row=c>>2, koff=(c&3)*8
#pragma unroll
        for (int i = 0; i < 2; i++) {
            int c = (wave * 2 + i) * 64 + lane;
            int row = c >> 2, koff = (c & 3) << 3;
            g2lds16(&A[(m0 + row) * K + k0 + koff], &As[(wave * 2 + i) * 512]);
            g2lds16(&Bt[(nb0 + row) * K + k0 + koff], &Bs[(wave * 2 + i) * 512]);
        }
        __syncthreads();  // drains vmcnt -> staging complete
        v8bf af[4], bfr[4];
#pragma unroll
        for (int i = 0; i < 4; i++) {
            af[i] = *(const v8bf*)(&As[(wm * 64 + i * 16 + n16) * 32 + kq * 8]);
            bfr[i] = *(const v8bf*)(&Bs[(wn * 64 + i * 16 + n16) * 32 + kq * 8]);
        }
#pragma unroll
        for (int mi = 0; mi < 4; mi++)
#pragma unroll
            for (int ni = 0; ni < 4; ni++)
                acc[mi][ni] = __builtin_amdgcn_mfma_f32_16x16x32_bf16(af[mi], bfr[ni],
                                                                     acc[mi][ni], 0, 0, 0);
        __syncthreads();
    }

    // epilogue: C/D layout col=lane&15, row=(lane>>4)*4+reg  [m89 verified]
#pragma unroll
    for (int mi = 0; mi < 4; mi++) {
#pragma unroll
        for (int ni = 0; ni < 4; ni++) {
#pragma unroll
            for (int r = 0; r < 4; r++) {
                long row = m0 + wm * 64 + mi * 16 + kq * 4 + r;
                long col = nb0 + wn * 64 + ni * 16 + n16;
                float v = acc[mi][ni][r];
                if (EPI == 0) {
                    int which = (int)(col / 768);
                    int c = (int)(col % 768);
                    int hh = c >> 6, ii = c & 63;
                    int bb = (int)(row >> 12), t = (int)(row & 4095);
                    size_t dst = (((size_t)bb * N_HEAD + hh) * T_SEQ + t) * D_HEAD + ii;
                    unsigned short bv = f2bf(v);
                    if (which == 0) Qb[dst] = bv;
                    else if (which == 1) Kb[dst] = bv;
                    else Vb[dst] = bv;
                } else if (EPI == 1) {
                    outF[row * 768 + col] = v + bias[col] + resid[row * 768 + col];
                } else {
                    float t = v + bias[col];
                    outB[row * 3072 + col] = f2bf(0.5f * t * (1.f + erff(t * 0.70710678118f)));
                }
            }
        }
    }
}

// ---------------- Flash attention (causal), bf16 Q/K/Vt -> bf16 y ------------
// Block = (pair,h,b): processes q-tiles {pair, 63-pair} -> 65 k-tiles/block.
// 4 waves x 16 q-rows, NO barriers (LDS P band is wave-private),
// K and Vt B-fragments loaded directly from global.
#define PSTR 72  // P band stride (shorts): 16B-aligned rows, <=2-way bank alias
__global__ __launch_bounds__(256) void attn_kernel(const unsigned short* __restrict__ Q,
                                                   const unsigned short* __restrict__ Kg,
                                                   const unsigned short* __restrict__ Vt,
                                                   unsigned short* __restrict__ y) {
    __shared__ unsigned short Ps[4 * 16 * PSTR];
    const int tid = threadIdx.x;
    const int wave = tid >> 6, lane = tid & 63;
    const int n16 = lane & 15, kq = lane >> 4;
    const int pair = blockIdx.x, h = blockIdx.y, b = blockIdx.z;
    const size_t hoff = (((size_t)b * N_HEAD + h) * T_SEQ) * D_HEAD;
    const unsigned short* Qh = Q + hoff;
    const unsigned short* Kh = Kg + hoff;
    const unsigned short* Vh = Vt + hoff;  // [64][T_SEQ]
    unsigned short* Pw = &Ps[wave * 16 * PSTR];
    const v4f vzero = {0.f, 0.f, 0.f, 0.f};

#pragma unroll 1
    for (int half = 0; half < 2; half++) {
        const int qt = half ? (63 - pair) : pair;
        // Q fragments (A-operand: A[m=lane&15][k=quad*8+j])
        const int qrow = qt * 64 + wave * 16 + n16;
        v8bf qf[2];
#pragma unroll
        for (int ks = 0; ks < 2; ks++)
            qf[ks] = *(const v8bf*)(&Qh[(size_t)qrow * D_HEAD + ks * 32 + kq * 8]);

        v4f o[4];
        float m_i[4], l_i[4];
#pragma unroll
        for (int r = 0; r < 4; r++) { m_i[r] = -__builtin_inff(); l_i[r] = 0.f; }
#pragma unroll
        for (int nt = 0; nt < 4; nt++) o[nt] = vzero;

        for (int kt = 0; kt <= qt; ++kt) {
            // S = Q * K^T
            v4f s[4];
#pragma unroll
            for (int nt = 0; nt < 4; nt++) s[nt] = vzero;
#pragma unroll
            for (int nt = 0; nt < 4; nt++)
#pragma unroll
                for (int ks = 0; ks < 2; ks++) {
                    v8bf kf = *(const v8bf*)(
                        &Kh[((size_t)kt * 64 + nt * 16 + n16) * D_HEAD + ks * 32 + kq * 8]);
                    s[nt] = __builtin_amdgcn_mfma_f32_16x16x32_bf16(qf[ks], kf, s[nt], 0, 0, 0);
                }
            // scale + causal mask (diagonal tile only)
            const int qbase = qt * 64 + wave * 16 + kq * 4;
#pragma unroll
            for (int nt = 0; nt < 4; nt++)
#pragma unroll
                for (int r = 0; r < 4; r++) {
                    float v = s[nt][r] * 0.125f;
                    if (kt == qt) {
                        int key = kt * 64 + nt * 16 + n16;
                        if (key > qbase + r) v = -__builtin_inff();
                    }
                    s[nt][r] = v;
                }
            // online softmax (rows live across the 16 lanes of each quad)
#pragma unroll
            for (int r = 0; r < 4; r++) {
                float mx = fmaxf(fmaxf(s[0][r], s[1][r]), fmaxf(s[2][r], s[3][r]));
                mx = fmaxf(mx, __shfl_xor(mx, 1));
                mx = fmaxf(mx, __shfl_xor(mx, 2));
                mx = fmaxf(mx, __shfl_xor(mx, 4));
                mx = fmaxf(mx, __shfl_xor(mx, 8));
                float mnew = fmaxf(m_i[r], mx);
                float alpha = __expf(m_i[r] - mnew);
                m_i[r] = mnew;
                float ps = 0.f;
#pragma unroll
                for (int nt = 0; nt < 4; nt++) {
                    float p = __expf(s[nt][r] - mnew);
                    s[nt][r] = p;
                    ps += p;
                }
                ps += __shfl_xor(ps, 1);
                ps += __shfl_xor(ps, 2);
                ps += __shfl_xor(ps, 4);
                ps += __shfl_xor(ps, 8);
                l_i[r] = l_i[r] * alpha + ps;
#pragma unroll
                for (int nt = 0; nt < 4; nt++) o[nt][r] *= alpha;
            }
            // P (C-layout) -> wave-private LDS band -> A-operand  [m120 pattern]
#pragma unroll
            for (int nt = 0; nt < 4; nt++)
#pragma unroll
                for (int r = 0; r < 4; r++)
                    Pw[(kq * 4 + r) * PSTR + nt * 16 + n16] = f2bf(s[nt][r]);
            // O += P * V  (Vt B-fragments contiguous from global)
#pragma unroll
            for (int ks = 0; ks < 2; ks++) {
                v8bf pa = *(const v8bf*)(&Pw[n16 * PSTR + ks * 32 + kq * 8]);
#pragma unroll
                for (int nt = 0; nt < 4; nt++) {
                    v8bf vb = *(const v8bf*)(
                        &Vh[(size_t)(nt * 16 + n16) * T_SEQ + kt * 64 + ks * 32 + kq * 8]);
                    o[nt] = __builtin_amdgcn_mfma_f32_16x16x32_bf16(pa, vb, o[nt], 0, 0, 0);
                }
            }
        }
        // epilogue: y[b][t][h*64+i] bf16
#pragma unroll
        for (int nt = 0; nt < 4; nt++)
#pragma unroll
            for (int r = 0; r < 4; r++) {
                int q = qt * 64 + wave * 16 + kq * 4 + r;
                float val = o[nt][r] / l_i[r];
                y[((size_t)b * T_SEQ + q) * D_EMB + h * 64 + nt * 16 + n16] = f2bf(val);
            }
    }
}

// ---------------- launch -----------------------------------------------------
extern "C" void kernel_launch(void* const* d_in, const int* in_sizes, int n_in,
                              void* d_out, int out_size, void* d_ws, size_t ws_size,
                              hipStream_t stream) {
    const float* x = (const float*)d_in[0];
    const float* ln1_g = (const float*)d_in[1];
    const float* ln1_b = (const float*)d_in[2];
    const float* wqkv_w = (const float*)d_in[3];
    const float* wo_w = (const float*)d_in[4];
    const float* wo_b = (const float*)d_in[5];
    const float* ln2_g = (const float*)d_in[6];
    const float* ln2_b = (const float*)d_in[7];
    const float* w1_w = (const float*)d_in[8];
    const float* w1_b = (const float*)d_in[9];
    const float* w2_w = (const float*)d_in[10];
    const float* w2_b = (const float*)d_in[11];
    float* out = (float*)d_out;

    char* ws = (char*)d_ws;
    size_t off = 0;
    auto alloc = [&](size_t bytes) -> void* {
        void* p = ws + off;
        off += (bytes + 255) & ~(size_t)255;
        return p;
    };
    unsigned short* xn = (unsigned short*)alloc((size_t)NTOK * D_EMB * 2);  // ln out
    unsigned short* wqkvT = (unsigned short*)alloc((size_t)2304 * 768 * 2);
    unsigned short* woT = (unsigned short*)alloc((size_t)768 * 768 * 2);
    unsigned short* w1T = (unsigned short*)alloc((size_t)3072 * 768 * 2);
    unsigned short* w2T = (unsigned short*)alloc((size_t)768 * 3072 * 2);
    unsigned short* Qb = (unsigned short*)alloc((size_t)NTOK * D_EMB * 2);
    unsigned short* Kb = (unsigned short*)alloc((size_t)NTOK * D_EMB * 2);
    unsigned short* Vb = (unsigned short*)alloc((size_t)NTOK * D_EMB * 2);
    unsigned short* yb = (unsigned short*)alloc((size_t)NTOK * D_EMB * 2);
    float* res1 = (float*)alloc((size_t)NTOK * D_EMB * 4);
    // overlays (sized regions above are dead at time of reuse):
    unsigned short* Vtb = xn;   // V^T lives only during attn; ln2 rewrites xn after
    unsigned short* hbuf = Qb;  // w1 output (50.3MB) spans Qb..yb, all dead by then

    dim3 tb(32, 8);
    tcast_kernel<<<dim3(2304 / 32, 768 / 32), tb, 0, stream>>>(wqkv_w, wqkvT, 768, 2304);
    tcast_kernel<<<dim3(768 / 32, 768 / 32), tb, 0, stream>>>(wo_w, woT, 768, 768);
    tcast_kernel<<<dim3(3072 / 32, 768 / 32), tb, 0, stream>>>(w1_w, w1T, 768, 3072);
    tcast_kernel<<<dim3(768 / 32, 3072 / 32), tb, 0, stream>>>(w2_w, w2T, 3072, 768);

    ln_kernel<<<NTOK, 256, 0, stream>>>(x, ln1_g, ln1_b, xn);

    gemm_kernel<0><<<dim3(2304 / 128, NTOK / 128), 256, 0, stream>>>(
        xn, wqkvT, 768, nullptr, nullptr, nullptr, nullptr, Qb, Kb, Vb);

    vtrans_kernel<<<dim3(T_SEQ / 32, 2, 2 * N_HEAD), tb, 0, stream>>>(Vb, Vtb);

    attn_kernel<<<dim3(32, N_HEAD, 2), 256, 0, stream>>>(Qb, Kb, Vtb, yb);

    gemm_kernel<1><<<dim3(768 / 128, NTOK / 128), 256, 0, stream>>>(
        yb, woT, 768, wo_b, x, res1, nullptr, nullptr, nullptr, nullptr);

    ln_kernel<<<NTOK, 256, 0, stream>>>(res1, ln2_g, ln2_b, xn);

    gemm_kernel<2><<<dim3(3072 / 128, NTOK / 128), 256, 0, stream>>>(
        xn, w1T, 768, w1_b, nullptr, nullptr, hbuf, nullptr, nullptr, nullptr);

    gemm_kernel<1><<<dim3(768 / 128, NTOK / 128), 256, 0, stream>>>(
        hbuf, w2T, 3072, w2_b, res1, out, nullptr, nullptr, nullptr, nullptr);
}